// Round 6
// baseline (253.082 us; speedup 1.0000x reference)
//
#include <hip/hip_runtime.h>
#include <hip/hip_bf16.h>
#include <stdint.h>

#define T_DIM 256
#define B_DIM 128
#define I_DIM 512
#define H_DIM 1024
#define M_DIM (T_DIM * B_DIM)

typedef __attribute__((ext_vector_type(4))) float f32x4;
typedef __attribute__((ext_vector_type(8))) short short8;  // 8 bf16 in 4 VGPRs

__device__ inline unsigned short f2bf(float f) {
    __hip_bfloat16 h = __float2bfloat16(f);  // RNE
    unsigned short u;
    __builtin_memcpy(&u, &h, sizeof(u));
    return u;
}

// async 16B global->LDS (DMA, no VGPR trip). LDS dest is lane-linear.
__device__ inline void gload_lds16(const void* g, void* l) {
    __builtin_amdgcn_global_load_lds(
        (const __attribute__((address_space(1))) uint32_t*)g,
        (__attribute__((address_space(3))) uint32_t*)l, 16, 0, 0);
}

// ---------------------------------------------------------------------------
// pack_W: W_ih (1024x512) f32 -> bf16 swizzled tile images (8 tiles of
// [kst][row][slot]); granule (r,s) holds src cols kst*64+(s^(r&7))*8..+8.
// GEMM stages linearly via gload_lds, reads granule g of row r at slot
// g^(r&7). 2 MB read / 1 MB write — ~1 us.
// ---------------------------------------------------------------------------
__global__ void pack_W(const float* __restrict__ W, unsigned short* __restrict__ Wp) {
    int id = blockIdx.x * 256 + threadIdx.x;  // 0..65535
    int slot = id & 7;
    int row = (id >> 3) & 127;
    int kst = (id >> 10) & 7;
    int nt = id >> 13;
    int g = slot ^ (row & 7);
    const float* s = W + (size_t)(nt * 128 + row) * I_DIM + kst * 64 + g * 8;
    f32x4 lo = *(const f32x4*)s;
    f32x4 hi = *(const f32x4*)(s + 4);
    union { unsigned short us[8]; short8 v; } pk;
#pragma unroll
    for (int j = 0; j < 4; ++j) { pk.us[j] = f2bf(lo[j]); pk.us[4 + j] = f2bf(hi[j]); }
    *(short8*)(Wp + (size_t)id * 8) = pk.v;
}

// ---------------------------------------------------------------------------
// bias_dot: biasall[b][h] = hidden[b,:].W_hh[h,:] + b_ih[h] + b_hh[h] (f32).
// Grid 256: block owns 4 h x 128 b (reuse-tiled: 528 KB cache reads/block,
// ~135 MB L2 aggregate, ~4 us).
// ---------------------------------------------------------------------------
__global__ __launch_bounds__(256) void bias_dot(
    const float* __restrict__ hidden, const float* __restrict__ W_hh,
    const float* __restrict__ b_ih, const float* __restrict__ b_hh,
    float* __restrict__ biasall) {
    const int b = threadIdx.x & 127;
    const int h0 = blockIdx.x * 4 + (threadIdx.x >> 7) * 2;
    const float* hr = hidden + (size_t)b * H_DIM;
#pragma unroll
    for (int q = 0; q < 2; ++q) {
        const int h = h0 + q;
        const float* wr = W_hh + (size_t)h * H_DIM;
        float s = 0.f;
#pragma unroll 4
        for (int k = 0; k < H_DIM; k += 4) {
            f32x4 a = *(const f32x4*)(hr + k);
            f32x4 w = *(const f32x4*)(wr + k);
            s += a[0] * w[0] + a[1] * w[1] + a[2] * w[2] + a[3] * w[3];
        }
        biasall[(size_t)b * H_DIM + h] = s + b_ih[h] + b_hh[h];
    }
}

// ---------------------------------------------------------------------------
// gemm6: out[m][h] = relu(x[m].W_ih[h] + biasall[m&127][h]).
// 128x128 tile, BK=64, 256 thr (4 waves 2x2), 16x16x32 bf16 MFMA,
// 2 blocks/CU (64 KB LDS dbuf). A reg-staged (f32 loads issued one tile
// early, cvt+ds_write after the freeing barrier); B gload_lds from packed
// Wp. Counted vmcnt keeps prefetch loads alive across barriers.
// ABL: 0 = real kernel; 1 = staging-only (no MFMA, keep-alive asm);
//      2 = compute-only (no global traffic / vm waits). ABL!=0 stores
//      compressed acc to scratch C (timing probes).
// ---------------------------------------------------------------------------
template <int ABL>
__global__ __launch_bounds__(256, 2) void gemm6(
    const float* __restrict__ X, const unsigned short* __restrict__ Wp,
    const float* __restrict__ biasall, float* __restrict__ C,
    float* __restrict__ Clast) {
    __shared__ unsigned short As[2][128 * 64];  // 16 KB each
    __shared__ unsigned short Bs[2][128 * 64];

    const int tid = threadIdx.x;
    const int lane = tid & 63;
    const int wid = tid >> 6;
    const int wr = wid >> 1, wc = wid & 1;
    const int llo = lane & 15, lhi = lane >> 4;

    // XCD-aware bijective swizzle (grid 2048 % 8 == 0)
    const int orig = blockIdx.x;
    const int wg = (orig & 7) * 256 + (orig >> 3);
    const int mt = wg >> 3, nt = wg & 7;
    const int m0 = mt * 128, n0 = nt * 128;

    // A staging geometry (v2-proven): thread handles rows srow+g*32, granule c8
    const int srow = tid >> 3, c8 = tid & 7;
    const int slot8 = (c8 ^ (srow & 7)) * 8;  // g-invariant
    const float* Aptr = X + (size_t)(m0 + srow) * I_DIM + c8 * 8;
    const unsigned short* Bbase = Wp + (size_t)nt * 65536 + (size_t)tid * 8;

    f32x4 pfa[4][2], pfb[4][2];  // two in-flight A register sets

    auto issueA = [&](int kst, f32x4 (&pf)[4][2]) {
#pragma unroll
        for (int g = 0; g < 4; ++g) {
            const float* p = Aptr + (size_t)g * 32 * I_DIM + kst * 64;
            pf[g][0] = *(const f32x4*)p;
            pf[g][1] = *(const f32x4*)(p + 4);
        }
    };
    auto writeA = [&](int buf, f32x4 (&pf)[4][2]) {
#pragma unroll
        for (int g = 0; g < 4; ++g) {
            union { unsigned short s[8]; short8 v; } pk;
#pragma unroll
            for (int j = 0; j < 4; ++j) {
                pk.s[j] = f2bf(pf[g][0][j]);
                pk.s[4 + j] = f2bf(pf[g][1][j]);
            }
            *(short8*)&As[buf][(srow + g * 32) * 64 + slot8] = pk.v;
        }
    };
    auto issueB = [&](int kst, int buf) {
#pragma unroll
        for (int gg = 0; gg < 4; ++gg)
            gload_lds16(Bbase + kst * 8192 + gg * 2048,
                        (char*)&Bs[buf][0] + (gg * 256 + tid) * 16);
    };

    f32x4 acc[4][4] = {};

    auto compute = [&](int buf) {
        __builtin_amdgcn_s_setprio(1);
#pragma unroll
        for (int ks = 0; ks < 2; ++ks) {
            short8 af[4], bfv[4];
#pragma unroll
            for (int mi = 0; mi < 4; ++mi) {
                int ar = wr * 64 + mi * 16 + llo;
                int slot = ((ks << 2) + lhi) ^ (ar & 7);
                af[mi] = *(const short8*)&As[buf][ar * 64 + slot * 8];
            }
#pragma unroll
            for (int ni = 0; ni < 4; ++ni) {
                int br = wc * 64 + ni * 16 + llo;
                int slot = ((ks << 2) + lhi) ^ (br & 7);
                bfv[ni] = *(const short8*)&Bs[buf][br * 64 + slot * 8];
            }
            if constexpr (ABL == 1) {
#pragma unroll
                for (int mi = 0; mi < 4; ++mi) asm volatile("" ::"v"(af[mi]));
#pragma unroll
                for (int ni = 0; ni < 4; ++ni) asm volatile("" ::"v"(bfv[ni]));
            } else {
#pragma unroll
                for (int mi = 0; mi < 4; ++mi)
#pragma unroll
                    for (int ni = 0; ni < 4; ++ni)
                        acc[mi][ni] = __builtin_amdgcn_mfma_f32_16x16x32_bf16(
                            af[mi], bfv[ni], acc[mi][ni], 0, 0, 0);
            }
        }
        __builtin_amdgcn_s_setprio(0);
    };

    // ---- prologue: fill buf0 completely, A(1) regs in flight ----
    if constexpr (ABL != 2) {
        issueA(0, pfa);  // 8 vmem
        issueB(0, 0);    // 4 vmem (younger)
        asm volatile("s_waitcnt vmcnt(4)" ::: "memory");  // A(0) landed
        writeA(0, pfa);
        issueA(1, pfb);  // 8 vmem
        asm volatile("s_waitcnt vmcnt(8)" ::: "memory");  // B(0) done; A(1) alive
        asm volatile("s_waitcnt lgkmcnt(0)" ::: "memory");
    }
    __builtin_amdgcn_s_barrier();

    // ---- main loop (fully unrolled; static guards; static reg-set naming) --
#pragma unroll
    for (int kt = 0; kt < 8; ++kt) {
        const int cur = kt & 1, nxt = cur ^ 1;
        if constexpr (ABL != 2) {
            if (kt < 7) {
                asm volatile("s_waitcnt vmcnt(0)" ::: "memory");  // A(kt+1) regs
                if (kt & 1) writeA(nxt, pfa); else writeA(nxt, pfb);
                issueB(kt + 1, nxt);  // 4 vmem
                if (kt < 6) { if (kt & 1) issueA(kt + 2, pfb); else issueA(kt + 2, pfa); }
            }
        }
        __builtin_amdgcn_sched_barrier(0);
        compute(cur);
        __builtin_amdgcn_sched_barrier(0);
        if (kt < 7) {
            if constexpr (ABL != 2) {
                if (kt < 6)
                    asm volatile("s_waitcnt vmcnt(8)" ::: "memory");  // B(kt+1) in; A(kt+2) alive
                else
                    asm volatile("s_waitcnt vmcnt(0)" ::: "memory");  // only B(7) in flight
                asm volatile("s_waitcnt lgkmcnt(0)" ::: "memory");
            }
            __builtin_amdgcn_s_barrier();
        }
    }

    // ---- epilogue ----
    if constexpr (ABL == 0) {
        const bool last_tile = (m0 == M_DIM - 128);
#pragma unroll
        for (int mi = 0; mi < 4; ++mi) {
#pragma unroll
            for (int ni = 0; ni < 4; ++ni) {
                int col = n0 + wc * 64 + ni * 16 + llo;
                int rowb = m0 + wr * 64 + mi * 16 + lhi * 4;
#pragma unroll
                for (int r = 0; r < 4; ++r) {
                    int row = rowb + r;
                    float v = acc[mi][ni][r] + biasall[(row & 127) * H_DIM + col];
                    v = fmaxf(v, 0.0f);
                    C[(size_t)row * H_DIM + col] = v;
                    if (last_tile) Clast[(row & 127) * H_DIM + col] = v;
                }
            }
        }
    } else {
        // compressed coalesced store of acc to scratch (keeps store count)
        float* S = C + (size_t)blockIdx.x * 4096;
#pragma unroll
        for (int mi = 0; mi < 4; ++mi)
#pragma unroll
            for (int ni = 0; ni < 4; ++ni)
#pragma unroll
                for (int r = 0; r < 4; ++r)
                    S[((mi * 4 + ni) * 4 + r) * 256 + tid] = acc[mi][ni][r];
    }
}

extern "C" void kernel_launch(void* const* d_in, const int* in_sizes, int n_in,
                              void* d_out, int out_size, void* d_ws, size_t ws_size,
                              hipStream_t stream) {
    const float* x = (const float*)d_in[0];       // (T,B,I)
    const float* hidden = (const float*)d_in[1];  // (B,H)
    const float* W_ih = (const float*)d_in[2];    // (H,I)
    const float* W_hh = (const float*)d_in[3];    // (H,H)
    const float* b_ih = (const float*)d_in[4];    // (H,)
    const float* b_hh = (const float*)d_in[5];    // (H,)

    float* out = (float*)d_out;                              // (T,B,H)
    float* out_last = out + (size_t)T_DIM * B_DIM * H_DIM;   // (B,H)

    // ws: [0,512K) biasall f32 ; [512K,1.5M) Wp bf16 ; [1.5M,+33.6M) abl scratch
    float* biasall = (float*)d_ws;
    unsigned short* Wp = (unsigned short*)((char*)d_ws + 512 * 1024);
    float* ablC = (float*)((char*)d_ws + 1536 * 1024);
    const size_t abl_need = 1536 * 1024 + (size_t)2048 * 4096 * 4;

    bias_dot<<<dim3(256), dim3(256), 0, stream>>>(hidden, W_hh, b_ih, b_hh, biasall);
    pack_W<<<dim3(256), dim3(256), 0, stream>>>(W_ih, Wp);
    gemm6<0><<<dim3(2048), dim3(256), 0, stream>>>(x, Wp, biasall, out, out_last);

    // ---- timing ablation probes (results discarded; top-5 rocprof rows) ----
    if (ws_size >= abl_need) {
        gemm6<1><<<dim3(2048), dim3(256), 0, stream>>>(x, Wp, biasall, ablC, nullptr);
        gemm6<2><<<dim3(2048), dim3(256), 0, stream>>>(x, Wp, biasall, ablC, nullptr);
    }
}

// Round 7
// 187.707 us; speedup vs baseline: 1.3483x; 1.3483x over previous
//
#include <hip/hip_runtime.h>
#include <hip/hip_bf16.h>
#include <stdint.h>

#define T_DIM 256
#define B_DIM 128
#define I_DIM 512
#define H_DIM 1024
#define M_DIM (T_DIM * B_DIM)

typedef __attribute__((ext_vector_type(4))) float f32x4;
typedef __attribute__((ext_vector_type(8))) short short8;  // 8 bf16 in 4 VGPRs

__device__ inline unsigned short f2bf(float f) {
    __hip_bfloat16 h = __float2bfloat16(f);  // RNE
    unsigned short u;
    __builtin_memcpy(&u, &h, sizeof(u));
    return u;
}

// async 16B global->LDS (DMA). LDS dest lane-linear; swizzle baked into the
// packed GLOBAL image (both-sides involution, proven 0-conflict in R1-R5).
__device__ inline void gload_lds16(const void* g, void* l) {
    __builtin_amdgcn_global_load_lds(
        (const __attribute__((address_space(1))) uint32_t*)g,
        (__attribute__((address_space(3))) uint32_t*)l, 16, 0, 0);
}

template <int N>
__device__ inline void vwait() {
    if constexpr (N == 0)       asm volatile("s_waitcnt vmcnt(0)" ::: "memory");
    else if constexpr (N == 2)  asm volatile("s_waitcnt vmcnt(2)" ::: "memory");
    else if constexpr (N == 4)  asm volatile("s_waitcnt vmcnt(4)" ::: "memory");
    else if constexpr (N == 8)  asm volatile("s_waitcnt vmcnt(8)" ::: "memory");
    else if constexpr (N == 10) asm volatile("s_waitcnt vmcnt(10)" ::: "memory");
    else                        asm volatile("s_waitcnt vmcnt(12)" ::: "memory");
}

// ---------------------------------------------------------------------------
// pack_both: f32 rows (stride 512) -> bf16 swizzled 128-row tile images.
// Tiles 0..255 = x, 256..263 = W_ih. Per tile: [kst][row][slot] granules of
// 8 bf16; granule (r,s) holds src cols kst*64+(s^(r&7))*8..+8. A 16 KB
// (tile,kst) chunk is exactly one GEMM half-tile, staged lane-linearly.
// ---------------------------------------------------------------------------
__global__ void pack_both(const float* __restrict__ x,
                          const float* __restrict__ W,
                          unsigned short* __restrict__ dst) {
    int id = blockIdx.x * 256 + threadIdx.x;  // 0 .. 264*8192-1
    int slot = id & 7;
    int row = (id >> 3) & 127;
    int kst = (id >> 10) & 7;
    int tile = id >> 13;
    int g = slot ^ (row & 7);
    const float* base = (tile < 256) ? (x + (size_t)tile * 128 * I_DIM)
                                     : (W + (size_t)(tile - 256) * 128 * I_DIM);
    const float* s = base + (size_t)row * I_DIM + kst * 64 + g * 8;
    f32x4 lo = *(const f32x4*)s;
    f32x4 hi = *(const f32x4*)(s + 4);
    union { unsigned short us[8]; short8 v; } pk;
#pragma unroll
    for (int j = 0; j < 4; ++j) { pk.us[j] = f2bf(lo[j]); pk.us[4 + j] = f2bf(hi[j]); }
    *(short8*)(dst + (size_t)id * 8) = pk.v;
}

// ---------------------------------------------------------------------------
// bias_dot: biasall[b][h] = hidden[b,:].W_hh[h,:] + b_ih[h] + b_hh[h] (f32).
// Grid 256: block owns 4 h x 128 b.
// ---------------------------------------------------------------------------
__global__ __launch_bounds__(256) void bias_dot(
    const float* __restrict__ hidden, const float* __restrict__ W_hh,
    const float* __restrict__ b_ih, const float* __restrict__ b_hh,
    float* __restrict__ biasall) {
    const int b = threadIdx.x & 127;
    const int h0 = blockIdx.x * 4 + (threadIdx.x >> 7) * 2;
    const float* hr = hidden + (size_t)b * H_DIM;
#pragma unroll
    for (int q = 0; q < 2; ++q) {
        const int h = h0 + q;
        const float* wr = W_hh + (size_t)h * H_DIM;
        float s = 0.f;
#pragma unroll 4
        for (int k = 0; k < H_DIM; k += 4) {
            f32x4 a = *(const f32x4*)(hr + k);
            f32x4 w = *(const f32x4*)(wr + k);
            s += a[0] * w[0] + a[1] * w[1] + a[2] * w[2] + a[3] * w[3];
        }
        biasall[(size_t)b * H_DIM + h] = s + b_ih[h] + b_hh[h];
    }
}

// ---------------------------------------------------------------------------
// gemm8: 8-phase 256x256 GEMM. out[m][h] = relu(Xp[m].Wp[h] + biasall[m&127][h]).
// 512 thr = 8 waves (2M x 4N); wave tile 128m x 64n, ROW-INTERLEAVED mapping:
//   out row = m0 + mi*32 + wm*16 + (lane>>4)*4 + r   (mi 0..7)
//   out col = n0 + ni*64 + wn*16 + (lane&15)         (ni 0..3)
// so LDS half-tiles (128 rows) map to quadrant halves (mh = mi>>2, nh = ni>>1).
// LDS 128 KB: [A|B] x [buf0|buf1] x [h0|h1] 16 KB chunks (= pack image chunks).
// Per K-tile t (buf = t&1), 4 phases (mh,nh): q0(0,0) q1(0,1) q2(1,0) q3(1,1).
// Last LDS reads: A-h0 @q0, B-h0 @q0, B-h1 @q1, A-h1 @q2  ==>  issue slots
// (last-read P -> safe issue P+2, all with 6-phase lead, 2 loads per half):
//   q0: stage A-h1[t+1];  q2: stage A-h0[t+2], B-h0[t+2];  q3: stage B-h1[t+2]
// Waits (counted, never drain; loads younger than needed half x 2):
//   q0: vmcnt(12)  q1: vmcnt(10)  q2: vmcnt(12)  q3: none   (tail: 4/2/8,0)
// ---------------------------------------------------------------------------
__global__ __launch_bounds__(512, 2) void gemm8(
    const unsigned short* __restrict__ Xp, const unsigned short* __restrict__ Wp,
    const float* __restrict__ biasall, float* __restrict__ C,
    float* __restrict__ Clast) {
    extern __shared__ char smem[];          // 131072 B
    char* AsB = smem;                        // 4 x 16384: (buf*2+h)
    char* BsB = smem + 65536;

    const int tid = threadIdx.x;
    const int lane = tid & 63;
    const int wid = tid >> 6;
    const int wm = wid >> 2, wn = wid & 3;   // 2M x 4N wave grid
    const int llo = lane & 15, lhi = lane >> 4;
    const int wml = wm * 16 + llo;           // A row within 128-half
    const int wnl = wn * 16 + llo;           // B row within 128-half
    const int l7a = wml & 7, l7b = wnl & 7;

    // XCD-aware swizzle (grid 512 % 8 == 0, bijective)
    const int orig = blockIdx.x;
    const int wg = (orig & 7) * 64 + (orig >> 3);
    const int mt = wg >> 2;                  // 128 m-supertiles (256 rows)
    const int nt = wg & 3;                   // 4 n-supertiles (256 cols)
    const int m0 = mt * 256, n0 = nt * 256;

    // stage one 16 KB half-tile (2 x gload_lds per thread)
    auto stageA = [&](int buf, int h, int kst) {
        const unsigned short* src =
            Xp + (size_t)(2 * mt + h) * 65536 + (size_t)kst * 8192 + tid * 8;
        char* dst = AsB + (buf * 2 + h) * 16384 + tid * 16;
        gload_lds16(src, dst);
        gload_lds16(src + 4096, dst + 8192);
    };
    auto stageB = [&](int buf, int h, int kst) {
        const unsigned short* src =
            Wp + (size_t)(2 * nt + h) * 65536 + (size_t)kst * 8192 + tid * 8;
        char* dst = BsB + (buf * 2 + h) * 16384 + tid * 16;
        gload_lds16(src, dst);
        gload_lds16(src + 4096, dst + 8192);
    };

    short8 af[4][2];        // A frags of current mh (4 mi x 2 ks)
    short8 b0[2][2];        // B frags nh=0 (2 ni x 2 ks), live q0->q2
    short8 b1[2][2];        // B frags nh=1, live q1->q3
    f32x4 acc[8][4] = {};

    auto loadA = [&](int buf, int mh) {
        const char* base = AsB + (buf * 2 + mh) * 16384;
#pragma unroll
        for (int mi = 0; mi < 4; ++mi) {
            int rp = mi * 32 + wml;
#pragma unroll
            for (int ks = 0; ks < 2; ++ks) {
                int slot = (ks * 4 + lhi) ^ l7a;
                af[mi][ks] = *(const short8*)(base + rp * 128 + slot * 16);
            }
        }
    };
    auto loadB = [&](int buf, int nh, short8 (&bf)[2][2]) {
        const char* base = BsB + (buf * 2 + nh) * 16384;
#pragma unroll
        for (int n2 = 0; n2 < 2; ++n2) {
            int rp = n2 * 64 + wnl;
#pragma unroll
            for (int ks = 0; ks < 2; ++ks) {
                int slot = (ks * 4 + lhi) ^ l7b;
                bf[n2][ks] = *(const short8*)(base + rp * 128 + slot * 16);
            }
        }
    };
    auto quad = [&](int mh, int nh, short8 (&bf)[2][2]) {
        __builtin_amdgcn_s_setprio(1);
#pragma unroll
        for (int ks = 0; ks < 2; ++ks)
#pragma unroll
            for (int mi = 0; mi < 4; ++mi)
#pragma unroll
                for (int n2 = 0; n2 < 2; ++n2)
                    acc[mh * 4 + mi][nh * 2 + n2] =
                        __builtin_amdgcn_mfma_f32_16x16x32_bf16(
                            af[mi][ks], bf[n2][ks], acc[mh * 4 + mi][nh * 2 + n2],
                            0, 0, 0);
        __builtin_amdgcn_s_setprio(0);
    };

    // ---- prologue: 7 half-tiles (14 loads), chronological steady order ----
    stageA(0, 0, 0);  // Ah0[0]
    stageB(0, 0, 0);  // Bh0[0]
    stageB(0, 1, 0);  // Bh1[0]
    stageA(0, 1, 0);  // Ah1[0]
    stageA(1, 0, 1);  // Ah0[1]
    stageB(1, 0, 1);  // Bh0[1]
    stageB(1, 1, 1);  // Bh1[1]

    // ---- main loop: 8 K-tiles x 4 phases ----
#pragma unroll
    for (int t = 0; t < 8; ++t) {
        const int buf = t & 1;
        // q0 (mh0, nh0)
        if (t <= 6) stageA(buf ^ 1, 1, t + 1);          // Ah1[t+1]
        if (t <= 6) vwait<12>(); else vwait<4>();
        __builtin_amdgcn_s_barrier();
        loadA(buf, 0);
        loadB(buf, 0, b0);
        quad(0, 0, b0);
        // q1 (mh0, nh1)
        if (t <= 6) vwait<10>(); else vwait<2>();
        __builtin_amdgcn_s_barrier();
        loadB(buf, 1, b1);
        quad(0, 1, b1);
        // q2 (mh1, nh0)
        if (t <= 5) { stageA(buf, 0, t + 2); stageB(buf, 0, t + 2); }
        if (t <= 5) vwait<12>(); else if (t == 6) vwait<8>(); else vwait<0>();
        __builtin_amdgcn_s_barrier();
        loadA(buf, 1);
        quad(1, 0, b0);
        // q3 (mh1, nh1)
        if (t <= 5) stageB(buf, 1, t + 2);               // Bh1[t+2]
        __builtin_amdgcn_s_barrier();
        quad(1, 1, b1);
    }

    // ---- epilogue: bias + relu + store (+ out_last from final 128 rows) ----
    const bool last_tile = (mt == 127);
#pragma unroll
    for (int mi8 = 0; mi8 < 8; ++mi8) {
#pragma unroll
        for (int ni4 = 0; ni4 < 4; ++ni4) {
            int col = n0 + ni4 * 64 + wnl;
            int rowb = m0 + mi8 * 32 + wm * 16 + lhi * 4;
#pragma unroll
            for (int r = 0; r < 4; ++r) {
                int row = rowb + r;
                float v = acc[mi8][ni4][r] + biasall[(row & 127) * H_DIM + col];
                v = fmaxf(v, 0.0f);
                C[(size_t)row * H_DIM + col] = v;
                if (last_tile && row >= M_DIM - 128)
                    Clast[(row & 127) * H_DIM + col] = v;
            }
        }
    }
}

// ---------------------------------------------------------------------------
// Fallback reg-staged f32 GEMM (v2-derived, bench-passed lineage) if ws small.
// ---------------------------------------------------------------------------
__global__ __launch_bounds__(256, 2) void gemm_bt(
    const float* __restrict__ A, const float* __restrict__ Bm,
    int M, int N, int K, const float* __restrict__ bias0,
    float* __restrict__ C, float* __restrict__ Clast) {
    __shared__ unsigned short As[128 * 64];
    __shared__ unsigned short Bs[128 * 64];
    const int tid = threadIdx.x;
    const int wid = tid >> 6, lane = tid & 63;
    const int wr = wid >> 1, wc = wid & 1;
    const int lhi = lane >> 4, llo = lane & 15;
    const int orig = blockIdx.x, nwg = gridDim.x;
    const int wg = (nwg > 8 && (nwg & 7) == 0)
                       ? ((orig & 7) * (nwg >> 3) + (orig >> 3)) : orig;
    const int m0 = (wg >> 3) * 128, n0 = (wg & 7) * 128;
    const int srow = tid >> 3, c8 = tid & 7;
    const int slot8 = (c8 ^ (srow & 7)) * 8;
    const float* Aptr = A + (size_t)(m0 + srow) * K + c8 * 8;
    const float* Bptr = Bm + (size_t)(n0 + srow) * K + c8 * 8;
    f32x4 pf[2][4][2];
    auto issue = [&](int k0) {
#pragma unroll
        for (int g = 0; g < 4; ++g) {
            const float* pa = Aptr + (size_t)g * 32 * K + k0;
            const float* pb = Bptr + (size_t)g * 32 * K + k0;
            pf[0][g][0] = *(const f32x4*)pa; pf[0][g][1] = *(const f32x4*)(pa + 4);
            pf[1][g][0] = *(const f32x4*)pb; pf[1][g][1] = *(const f32x4*)(pb + 4);
        }
    };
    auto write_lds = [&]() {
#pragma unroll
        for (int g = 0; g < 4; ++g) {
            union { unsigned short s[8]; short8 v; } pka, pkb;
#pragma unroll
            for (int j = 0; j < 4; ++j) {
                pka.s[j] = f2bf(pf[0][g][0][j]); pka.s[4 + j] = f2bf(pf[0][g][1][j]);
                pkb.s[j] = f2bf(pf[1][g][0][j]); pkb.s[4 + j] = f2bf(pf[1][g][1][j]);
            }
            *(short8*)&As[(srow + g * 32) * 64 + slot8] = pka.v;
            *(short8*)&Bs[(srow + g * 32) * 64 + slot8] = pkb.v;
        }
    };
    f32x4 acc[4][4] = {};
    auto compute = [&]() {
#pragma unroll
        for (int ks = 0; ks < 2; ++ks) {
            short8 afr[4], bfr[4];
#pragma unroll
            for (int mi = 0; mi < 4; ++mi) {
                int ar = wr * 64 + mi * 16 + llo;
                afr[mi] = *(const short8*)&As[ar * 64 + (((ks << 2) + lhi) ^ (ar & 7)) * 8];
            }
#pragma unroll
            for (int ni = 0; ni < 4; ++ni) {
                int br = wc * 64 + ni * 16 + llo;
                bfr[ni] = *(const short8*)&Bs[br * 64 + (((ks << 2) + lhi) ^ (br & 7)) * 8];
            }
#pragma unroll
            for (int mi = 0; mi < 4; ++mi)
#pragma unroll
                for (int ni = 0; ni < 4; ++ni)
                    acc[mi][ni] = __builtin_amdgcn_mfma_f32_16x16x32_bf16(
                        afr[mi], bfr[ni], acc[mi][ni], 0, 0, 0);
        }
    };
    issue(0); write_lds(); __syncthreads();
    for (int k0 = 64; k0 < K; k0 += 64) {
        issue(k0); compute(); __syncthreads(); write_lds(); __syncthreads();
    }
    compute();
    const bool last_tile = (m0 == M - 128);
#pragma unroll
    for (int mi = 0; mi < 4; ++mi)
#pragma unroll
        for (int ni = 0; ni < 4; ++ni) {
            int col = n0 + wc * 64 + ni * 16 + llo;
            int rowb = m0 + wr * 64 + mi * 16 + lhi * 4;
#pragma unroll
            for (int r = 0; r < 4; ++r) {
                int row = rowb + r;
                float v = fmaxf(acc[mi][ni][r] + bias0[(row & 127) * N + col], 0.f);
                C[(size_t)row * N + col] = v;
                if (last_tile) Clast[(row & 127) * N + col] = v;
            }
        }
}

extern "C" void kernel_launch(void* const* d_in, const int* in_sizes, int n_in,
                              void* d_out, int out_size, void* d_ws, size_t ws_size,
                              hipStream_t stream) {
    const float* x = (const float*)d_in[0];       // (T,B,I)
    const float* hidden = (const float*)d_in[1];  // (B,H)
    const float* W_ih = (const float*)d_in[2];    // (H,I)
    const float* W_hh = (const float*)d_in[3];    // (H,H)
    const float* b_ih = (const float*)d_in[4];    // (H,)
    const float* b_hh = (const float*)d_in[5];    // (H,)

    float* out = (float*)d_out;                              // (T,B,H)
    float* out_last = out + (size_t)T_DIM * B_DIM * H_DIM;   // (B,H)

    // ws: [0,512K) biasall f32 ; then Xp (256 tiles x 128 KB) ; Wp (8 tiles)
    float* biasall = (float*)d_ws;
    unsigned short* Xp = (unsigned short*)((char*)d_ws + 512 * 1024);
    unsigned short* Wp = Xp + (size_t)256 * 65536;
    const size_t ws_need = 512 * 1024 + (size_t)264 * 65536 * 2;

    bias_dot<<<dim3(256), dim3(256), 0, stream>>>(hidden, W_hh, b_ih, b_hh, biasall);

    if (ws_size >= ws_need) {
        pack_both<<<dim3(264 * 8192 / 256), dim3(256), 0, stream>>>(x, W_ih, Xp);
        hipFuncSetAttribute((const void*)gemm8,
                            hipFuncAttributeMaxDynamicSharedMemorySize, 131072);
        gemm8<<<dim3(512), dim3(512), 131072, stream>>>(Xp, Wp, biasall, out, out_last);
    } else {
        gemm_bt<<<dim3(M_DIM / 128 * (H_DIM / 128)), dim3(256), 0, stream>>>(
            x, W_ih, M_DIM, H_DIM, I_DIM, biasall, out, out_last);
    }
}

// Round 8
// 170.510 us; speedup vs baseline: 1.4843x; 1.1009x over previous
//
#include <hip/hip_runtime.h>
#include <hip/hip_bf16.h>
#include <stdint.h>

#define T_DIM 256
#define B_DIM 128
#define I_DIM 512
#define H_DIM 1024
#define M_DIM (T_DIM * B_DIM)

typedef __attribute__((ext_vector_type(4))) float f32x4;
typedef __attribute__((ext_vector_type(8))) short short8;  // 8 bf16 in 4 VGPRs

__device__ inline unsigned short f2bf(float f) {
    __hip_bfloat16 h = __float2bfloat16(f);  // RNE
    unsigned short u;
    __builtin_memcpy(&u, &h, sizeof(u));
    return u;
}

// async 16B global->LDS (DMA). LDS dest lane-linear; swizzle baked into the
// packed GLOBAL image (both-sides involution, 0 bank conflicts R1-R7).
__device__ inline void gload_lds16(const void* g, void* l) {
    __builtin_amdgcn_global_load_lds(
        (const __attribute__((address_space(1))) uint32_t*)g,
        (__attribute__((address_space(3))) uint32_t*)l, 16, 0, 0);
}

// ---------------------------------------------------------------------------
// pack_both: f32 rows (stride 512) -> bf16 swizzled 128-row tile images.
// Tiles 0..255 = x, 256..263 = W_ih. Per tile: [kst][row][slot] granules of
// 8 bf16; granule (r,s) holds src cols kst*64+(s^(r&7))*8..+8.
// kst-chunk = 16 KB; 64-row half-chunk = 8 KB (contiguous, r&7 preserved).
// ---------------------------------------------------------------------------
__global__ void pack_both(const float* __restrict__ x,
                          const float* __restrict__ W,
                          unsigned short* __restrict__ dst) {
    int id = blockIdx.x * 256 + threadIdx.x;  // 0 .. 264*8192-1
    int slot = id & 7;
    int row = (id >> 3) & 127;
    int kst = (id >> 10) & 7;
    int tile = id >> 13;
    int g = slot ^ (row & 7);
    const float* base = (tile < 256) ? (x + (size_t)tile * 128 * I_DIM)
                                     : (W + (size_t)(tile - 256) * 128 * I_DIM);
    const float* s = base + (size_t)row * I_DIM + kst * 64 + g * 8;
    f32x4 lo = *(const f32x4*)s;
    f32x4 hi = *(const f32x4*)(s + 4);
    union { unsigned short us[8]; short8 v; } pk;
#pragma unroll
    for (int j = 0; j < 4; ++j) { pk.us[j] = f2bf(lo[j]); pk.us[4 + j] = f2bf(hi[j]); }
    *(short8*)(dst + (size_t)id * 8) = pk.v;
}

// ---------------------------------------------------------------------------
// bias_dot: biasall[b][h] = hidden[b,:].W_hh[h,:] + b_ih[h] + b_hh[h] (f32).
// Grid 256: block owns 4 h x 128 b.
// ---------------------------------------------------------------------------
__global__ __launch_bounds__(256) void bias_dot(
    const float* __restrict__ hidden, const float* __restrict__ W_hh,
    const float* __restrict__ b_ih, const float* __restrict__ b_hh,
    float* __restrict__ biasall) {
    const int b = threadIdx.x & 127;
    const int h0 = blockIdx.x * 4 + (threadIdx.x >> 7) * 2;
    const float* hr = hidden + (size_t)b * H_DIM;
#pragma unroll
    for (int q = 0; q < 2; ++q) {
        const int h = h0 + q;
        const float* wr = W_hh + (size_t)h * H_DIM;
        float s = 0.f;
#pragma unroll 4
        for (int k = 0; k < H_DIM; k += 4) {
            f32x4 a = *(const f32x4*)(hr + k);
            f32x4 w = *(const f32x4*)(wr + k);
            s += a[0] * w[0] + a[1] * w[1] + a[2] * w[2] + a[3] * w[3];
        }
        biasall[(size_t)b * H_DIM + h] = s + b_ih[h] + b_hh[h];
    }
}

// ---------------------------------------------------------------------------
// gemm64: out[m][h] = relu(Xp[m].Wp[h] + biasall[m&127][h]).
// 64x128 tile (BMxBN), BK=64, 256 thr = 4 waves (2m x 2n, wave 32m x 64n).
// LDS 48 KB dbuf -> 3 blocks/CU = 12 waves/CU (the TLP lever). Counted
// s_waitcnt vmcnt(6): next tile's 6 gload_lds (2 A + 4 B) stay in flight
// across barriers; vmcnt never drains to 0 until the tail (R4-proven
// discipline, scaled 8->6 loads/step). Grid 4096, XCD-swizzled.
// ---------------------------------------------------------------------------
__global__ __launch_bounds__(256, 3) void gemm64(
    const unsigned short* __restrict__ Xp, const unsigned short* __restrict__ Wp,
    const float* __restrict__ biasall, float* __restrict__ C,
    float* __restrict__ Clast) {
    __shared__ unsigned short As[2][64 * 64];    // 8 KB each
    __shared__ unsigned short Bs[2][128 * 64];   // 16 KB each

    const int tid = threadIdx.x;
    const int lane = tid & 63;
    const int wid = tid >> 6;
    const int wm = wid >> 1, wn = wid & 1;       // 2m x 2n wave grid
    const int llo = lane & 15, lhi = lane >> 4;

    // XCD-aware bijective swizzle (grid 4096 % 8 == 0)
    const int orig = blockIdx.x;
    const int wg = (orig & 7) * 512 + (orig >> 3);
    const int mt = wg >> 3;                      // 512 m-tiles (64 rows)
    const int nt = wg & 7;                       // 8 n-tiles (128 cols)
    const int m0 = mt * 64, n0 = nt * 128;

    // A image address: 128-row pack tile mt>>1, 64-row half mt&1 (8 KB chunk)
    const unsigned short* Abase =
        Xp + (size_t)(mt >> 1) * 65536 + (size_t)(mt & 1) * 4096 + (size_t)tid * 8;
    const unsigned short* Bbase = Wp + (size_t)nt * 65536 + (size_t)tid * 8;

    auto stage = [&](int kst, int buf) {
        const unsigned short* a = Abase + (size_t)kst * 8192;
        const unsigned short* b = Bbase + (size_t)kst * 8192;
        // A: 8 KB = 2 x 16B per thread
        gload_lds16(a, (char*)As[buf] + tid * 16);
        gload_lds16(a + 2048, (char*)As[buf] + 4096 + tid * 16);
        // B: 16 KB = 4 x 16B per thread
#pragma unroll
        for (int g = 0; g < 4; ++g)
            gload_lds16(b + g * 2048, (char*)Bs[buf] + (g * 256 + tid) * 16);
    };

    f32x4 acc[2][4] = {};

    auto compute = [&](int buf) {
#pragma unroll
        for (int ks = 0; ks < 2; ++ks) {
            short8 af[2], bfv[4];
#pragma unroll
            for (int mi = 0; mi < 2; ++mi) {
                int ar = wm * 32 + mi * 16 + llo;
                int slot = ((ks << 2) + lhi) ^ (ar & 7);
                af[mi] = *(const short8*)&As[buf][ar * 64 + slot * 8];
            }
#pragma unroll
            for (int ni = 0; ni < 4; ++ni) {
                int br = wn * 64 + ni * 16 + llo;
                int slot = ((ks << 2) + lhi) ^ (br & 7);
                bfv[ni] = *(const short8*)&Bs[buf][br * 64 + slot * 8];
            }
#pragma unroll
            for (int mi = 0; mi < 2; ++mi)
#pragma unroll
                for (int ni = 0; ni < 4; ++ni)
                    acc[mi][ni] = __builtin_amdgcn_mfma_f32_16x16x32_bf16(
                        af[mi], bfv[ni], acc[mi][ni], 0, 0, 0);
        }
    };

    stage(0, 0);   // 6 loads in flight
    stage(1, 1);   // 12 in flight
#pragma unroll
    for (int kt = 0; kt < 8; ++kt) {
        const int buf = kt & 1;
        if (kt < 7)
            asm volatile("s_waitcnt vmcnt(6)" ::: "memory");  // tile kt landed
        else
            asm volatile("s_waitcnt vmcnt(0)" ::: "memory");
        __builtin_amdgcn_s_barrier();
        __builtin_amdgcn_sched_barrier(0);
        compute(buf);
        __builtin_amdgcn_sched_barrier(0);
        __builtin_amdgcn_s_barrier();             // buf free for reuse
        if (kt + 2 < 8) stage(kt + 2, buf);       // stays in flight across iters
    }

    // epilogue: bias + relu + store (+ out_last from final 128 rows)
    const bool last_tiles = (mt >= 510);
#pragma unroll
    for (int mi = 0; mi < 2; ++mi) {
#pragma unroll
        for (int ni = 0; ni < 4; ++ni) {
            int col = n0 + wn * 64 + ni * 16 + llo;
            int rowb = m0 + wm * 32 + mi * 16 + lhi * 4;
#pragma unroll
            for (int r = 0; r < 4; ++r) {
                int row = rowb + r;
                float v = acc[mi][ni][r] + biasall[(row & 127) * H_DIM + col];
                v = fmaxf(v, 0.0f);
                C[(size_t)row * H_DIM + col] = v;
                if (last_tiles) Clast[(row & 127) * H_DIM + col] = v;
            }
        }
    }
}

// ---------------------------------------------------------------------------
// Fallback reg-staged f32 GEMM (bench-passed lineage) if ws too small.
// ---------------------------------------------------------------------------
__global__ __launch_bounds__(256, 2) void gemm_bt(
    const float* __restrict__ A, const float* __restrict__ Bm,
    int M, int N, int K, const float* __restrict__ bias0,
    float* __restrict__ C, float* __restrict__ Clast) {
    __shared__ unsigned short As[128 * 64];
    __shared__ unsigned short Bs[128 * 64];
    const int tid = threadIdx.x;
    const int wid = tid >> 6, lane = tid & 63;
    const int wr = wid >> 1, wc = wid & 1;
    const int lhi = lane >> 4, llo = lane & 15;
    const int orig = blockIdx.x, nwg = gridDim.x;
    const int wg = (nwg > 8 && (nwg & 7) == 0)
                       ? ((orig & 7) * (nwg >> 3) + (orig >> 3)) : orig;
    const int m0 = (wg >> 3) * 128, n0 = (wg & 7) * 128;
    const int srow = tid >> 3, c8 = tid & 7;
    const int slot8 = (c8 ^ (srow & 7)) * 8;
    const float* Aptr = A + (size_t)(m0 + srow) * K + c8 * 8;
    const float* Bptr = Bm + (size_t)(n0 + srow) * K + c8 * 8;
    f32x4 pf[2][4][2];
    auto issue = [&](int k0) {
#pragma unroll
        for (int g = 0; g < 4; ++g) {
            const float* pa = Aptr + (size_t)g * 32 * K + k0;
            const float* pb = Bptr + (size_t)g * 32 * K + k0;
            pf[0][g][0] = *(const f32x4*)pa; pf[0][g][1] = *(const f32x4*)(pa + 4);
            pf[1][g][0] = *(const f32x4*)pb; pf[1][g][1] = *(const f32x4*)(pb + 4);
        }
    };
    auto write_lds = [&]() {
#pragma unroll
        for (int g = 0; g < 4; ++g) {
            union { unsigned short s[8]; short8 v; } pka, pkb;
#pragma unroll
            for (int j = 0; j < 4; ++j) {
                pka.s[j] = f2bf(pf[0][g][0][j]); pka.s[4 + j] = f2bf(pf[0][g][1][j]);
                pkb.s[j] = f2bf(pf[1][g][0][j]); pkb.s[4 + j] = f2bf(pf[1][g][1][j]);
            }
            *(short8*)&As[(srow + g * 32) * 64 + slot8] = pka.v;
            *(short8*)&Bs[(srow + g * 32) * 64 + slot8] = pkb.v;
        }
    };
    f32x4 acc[4][4] = {};
    auto compute = [&]() {
#pragma unroll
        for (int ks = 0; ks < 2; ++ks) {
            short8 afr[4], bfr[4];
#pragma unroll
            for (int mi = 0; mi < 4; ++mi) {
                int ar = wr * 64 + mi * 16 + llo;
                afr[mi] = *(const short8*)&As[ar * 64 + (((ks << 2) + lhi) ^ (ar & 7)) * 8];
            }
#pragma unroll
            for (int ni = 0; ni < 4; ++ni) {
                int br = wc * 64 + ni * 16 + llo;
                bfr[ni] = *(const short8*)&Bs[br * 64 + (((ks << 2) + lhi) ^ (br & 7)) * 8];
            }
#pragma unroll
            for (int mi = 0; mi < 4; ++mi)
#pragma unroll
                for (int ni = 0; ni < 4; ++ni)
                    acc[mi][ni] = __builtin_amdgcn_mfma_f32_16x16x32_bf16(
                        afr[mi], bfr[ni], acc[mi][ni], 0, 0, 0);
        }
    };
    issue(0); write_lds(); __syncthreads();
    for (int k0 = 64; k0 < K; k0 += 64) {
        issue(k0); compute(); __syncthreads(); write_lds(); __syncthreads();
    }
    compute();
    const bool last_tile = (m0 == M - 128);
#pragma unroll
    for (int mi = 0; mi < 4; ++mi)
#pragma unroll
        for (int ni = 0; ni < 4; ++ni) {
            int col = n0 + wc * 64 + ni * 16 + llo;
            int rowb = m0 + wr * 64 + mi * 16 + lhi * 4;
#pragma unroll
            for (int r = 0; r < 4; ++r) {
                int row = rowb + r;
                float v = fmaxf(acc[mi][ni][r] + bias0[(row & 127) * N + col], 0.f);
                C[(size_t)row * N + col] = v;
                if (last_tile) Clast[(row & 127) * N + col] = v;
            }
        }
}

extern "C" void kernel_launch(void* const* d_in, const int* in_sizes, int n_in,
                              void* d_out, int out_size, void* d_ws, size_t ws_size,
                              hipStream_t stream) {
    const float* x = (const float*)d_in[0];       // (T,B,I)
    const float* hidden = (const float*)d_in[1];  // (B,H)
    const float* W_ih = (const float*)d_in[2];    // (H,I)
    const float* W_hh = (const float*)d_in[3];    // (H,H)
    const float* b_ih = (const float*)d_in[4];    // (H,)
    const float* b_hh = (const float*)d_in[5];    // (H,)

    float* out = (float*)d_out;                              // (T,B,H)
    float* out_last = out + (size_t)T_DIM * B_DIM * H_DIM;   // (B,H)

    // ws: [0,512K) biasall f32 ; then Xp (256 tiles x 128 KB) ; Wp (8 tiles)
    float* biasall = (float*)d_ws;
    unsigned short* Xp = (unsigned short*)((char*)d_ws + 512 * 1024);
    unsigned short* Wp = Xp + (size_t)256 * 65536;
    const size_t ws_need = 512 * 1024 + (size_t)264 * 65536 * 2;

    bias_dot<<<dim3(256), dim3(256), 0, stream>>>(hidden, W_hh, b_ih, b_hh, biasall);

    if (ws_size >= ws_need) {
        pack_both<<<dim3(264 * 8192 / 256), dim3(256), 0, stream>>>(x, W_ih, Xp);
        gemm64<<<dim3(4096), dim3(256), 0, stream>>>(Xp, Wp, biasall, out, out_last);
    } else {
        gemm_bt<<<dim3(M_DIM / 128 * (H_DIM / 128)), dim3(256), 0, stream>>>(
            x, W_ih, M_DIM, H_DIM, I_DIM, biasall, out, out_last);
    }
}

// Round 9
// 117.229 us; speedup vs baseline: 2.1589x; 1.4545x over previous
//
#include <hip/hip_runtime.h>
#include <hip/hip_bf16.h>
#include <stdint.h>

#define T_DIM 256
#define B_DIM 128
#define I_DIM 512
#define H_DIM 1024
#define M_DIM (T_DIM * B_DIM)

#define PACK_BLOCKS (264 * 8192 / 256)  // 8448
#define BIAS_BLOCKS 512                 // 2048 waves, 64 outputs each

typedef __attribute__((ext_vector_type(4))) float f32x4;
typedef __attribute__((ext_vector_type(8))) short short8;  // 8 bf16 in 4 VGPRs

__device__ inline unsigned short f2bf(float f) {
    __hip_bfloat16 h = __float2bfloat16(f);  // RNE
    unsigned short u;
    __builtin_memcpy(&u, &h, sizeof(u));
    return u;
}

// async 16B global->LDS (DMA). LDS dest lane-linear; swizzle baked into the
// packed GLOBAL image (both-sides involution, 0 bank conflicts R1-R8).
__device__ inline void gload_lds16(const void* g, void* l) {
    __builtin_amdgcn_global_load_lds(
        (const __attribute__((address_space(1))) uint32_t*)g,
        (__attribute__((address_space(3))) uint32_t*)l, 16, 0, 0);
}

// ---------------------------------------------------------------------------
// prep<WITH_PACK>: fused pre-pass.
// Blocks [0, PACK_BLOCKS): pack x (tiles 0..255) and W_ih (tiles 256..263)
//   f32 -> bf16 swizzled 128-row tile images ([kst][row][slot] granules;
//   granule (r,s) holds src cols kst*64+(s^(r&7))*8..+8).
// Blocks [PACK_BLOCKS, +BIAS_BLOCKS): wave-cooperative bias:
//   biasall[b][h] = hidden[b,:].W_hh[h,:] + b_ih[h] + b_hh[h]  (f32 exact).
//   Wave owns 4 h x 16 b; W rows held in regs (coalesced 16B/lane spans the
//   4 KB row); hidden rows coalesced per-b; 64-lane shfl_xor butterfly.
// ---------------------------------------------------------------------------
template <bool WITH_PACK>
__global__ __launch_bounds__(256) void prep(
    const float* __restrict__ x, const float* __restrict__ W_ih,
    unsigned short* __restrict__ Xp,
    const float* __restrict__ hidden, const float* __restrict__ W_hh,
    const float* __restrict__ b_ih, const float* __restrict__ b_hh,
    float* __restrict__ biasall) {
    const int bid = blockIdx.x;
    const int tid = threadIdx.x;

    if (WITH_PACK && bid < PACK_BLOCKS) {
        int id = bid * 256 + tid;  // 0 .. 264*8192-1
        int slot = id & 7;
        int row = (id >> 3) & 127;
        int kst = (id >> 10) & 7;
        int tile = id >> 13;
        int g = slot ^ (row & 7);
        const float* base = (tile < 256)
                                ? (x + (size_t)tile * 128 * I_DIM)
                                : (W_ih + (size_t)(tile - 256) * 128 * I_DIM);
        const float* s = base + (size_t)row * I_DIM + kst * 64 + g * 8;
        f32x4 lo = *(const f32x4*)s;
        f32x4 hi = *(const f32x4*)(s + 4);
        union { unsigned short us[8]; short8 v; } pk;
#pragma unroll
        for (int j = 0; j < 4; ++j) {
            pk.us[j] = f2bf(lo[j]);
            pk.us[4 + j] = f2bf(hi[j]);
        }
        *(short8*)(Xp + (size_t)id * 8) = pk.v;
        return;
    }

    // ---- bias path ----
    const int pbase = WITH_PACK ? PACK_BLOCKS : 0;
    const int gw = (bid - pbase) * 4 + (tid >> 6);  // wave id 0..2047
    const int lane = tid & 63;
    const int h0 = (gw >> 3) * 4;    // 256 h-groups
    const int b0 = (gw & 7) * 16;    // 8 b-groups

    // W rows in registers: wreg[hh][it] covers cols it*256 + lane*4 .. +4
    f32x4 wreg[4][4];
#pragma unroll
    for (int hh = 0; hh < 4; ++hh)
#pragma unroll
        for (int it = 0; it < 4; ++it)
            wreg[hh][it] = *(const f32x4*)(W_hh + (size_t)(h0 + hh) * H_DIM +
                                           it * 256 + lane * 4);
    float bias2[4];
#pragma unroll
    for (int hh = 0; hh < 4; ++hh) bias2[hh] = b_ih[h0 + hh] + b_hh[h0 + hh];

#pragma unroll
    for (int b = 0; b < 16; ++b) {
        f32x4 hreg[4];
#pragma unroll
        for (int it = 0; it < 4; ++it)
            hreg[it] = *(const f32x4*)(hidden + (size_t)(b0 + b) * H_DIM +
                                       it * 256 + lane * 4);
        float s[4] = {0.f, 0.f, 0.f, 0.f};
#pragma unroll
        for (int hh = 0; hh < 4; ++hh)
#pragma unroll
            for (int it = 0; it < 4; ++it)
#pragma unroll
                for (int j = 0; j < 4; ++j)
                    s[hh] += wreg[hh][it][j] * hreg[it][j];
#pragma unroll
        for (int m = 1; m < 64; m <<= 1)
#pragma unroll
            for (int hh = 0; hh < 4; ++hh) s[hh] += __shfl_xor(s[hh], m, 64);
        if (lane == 0) {
#pragma unroll
            for (int hh = 0; hh < 4; ++hh)
                biasall[(size_t)(b0 + b) * H_DIM + h0 + hh] = s[hh] + bias2[hh];
        }
    }
}

// ---------------------------------------------------------------------------
// gemm64: out[m][h] = relu(Xp[m].Wp[h] + biasall[m&127][h]).
// 64x128 tile, BK=64, 256 thr (2m x 2n waves). LDS 48 KB dbuf -> 3 blocks/CU
// (12 waves/CU TLP). Counted vmcnt(6): next tile's 6 gload_lds stay in
// flight across barriers; drains only in the tail. Grid 4096, XCD-swizzled.
// Unchanged from R8 (benched: < 84 us, 0 bank conflicts).
// ---------------------------------------------------------------------------
__global__ __launch_bounds__(256, 3) void gemm64(
    const unsigned short* __restrict__ Xp, const unsigned short* __restrict__ Wp,
    const float* __restrict__ biasall, float* __restrict__ C,
    float* __restrict__ Clast) {
    __shared__ unsigned short As[2][64 * 64];    // 8 KB each
    __shared__ unsigned short Bs[2][128 * 64];   // 16 KB each

    const int tid = threadIdx.x;
    const int lane = tid & 63;
    const int wid = tid >> 6;
    const int wm = wid >> 1, wn = wid & 1;
    const int llo = lane & 15, lhi = lane >> 4;

    const int orig = blockIdx.x;
    const int wg = (orig & 7) * 512 + (orig >> 3);
    const int mt = wg >> 3;                      // 512 m-tiles (64 rows)
    const int nt = wg & 7;                       // 8 n-tiles (128 cols)
    const int m0 = mt * 64, n0 = nt * 128;

    const unsigned short* Abase =
        Xp + (size_t)(mt >> 1) * 65536 + (size_t)(mt & 1) * 4096 + (size_t)tid * 8;
    const unsigned short* Bbase = Wp + (size_t)nt * 65536 + (size_t)tid * 8;

    auto stage = [&](int kst, int buf) {
        const unsigned short* a = Abase + (size_t)kst * 8192;
        const unsigned short* b = Bbase + (size_t)kst * 8192;
        gload_lds16(a, (char*)As[buf] + tid * 16);
        gload_lds16(a + 2048, (char*)As[buf] + 4096 + tid * 16);
#pragma unroll
        for (int g = 0; g < 4; ++g)
            gload_lds16(b + g * 2048, (char*)Bs[buf] + (g * 256 + tid) * 16);
    };

    f32x4 acc[2][4] = {};

    auto compute = [&](int buf) {
#pragma unroll
        for (int ks = 0; ks < 2; ++ks) {
            short8 af[2], bfv[4];
#pragma unroll
            for (int mi = 0; mi < 2; ++mi) {
                int ar = wm * 32 + mi * 16 + llo;
                int slot = ((ks << 2) + lhi) ^ (ar & 7);
                af[mi] = *(const short8*)&As[buf][ar * 64 + slot * 8];
            }
#pragma unroll
            for (int ni = 0; ni < 4; ++ni) {
                int br = wn * 64 + ni * 16 + llo;
                int slot = ((ks << 2) + lhi) ^ (br & 7);
                bfv[ni] = *(const short8*)&Bs[buf][br * 64 + slot * 8];
            }
#pragma unroll
            for (int mi = 0; mi < 2; ++mi)
#pragma unroll
                for (int ni = 0; ni < 4; ++ni)
                    acc[mi][ni] = __builtin_amdgcn_mfma_f32_16x16x32_bf16(
                        af[mi], bfv[ni], acc[mi][ni], 0, 0, 0);
        }
    };

    stage(0, 0);
    stage(1, 1);
#pragma unroll
    for (int kt = 0; kt < 8; ++kt) {
        const int buf = kt & 1;
        if (kt < 7)
            asm volatile("s_waitcnt vmcnt(6)" ::: "memory");
        else
            asm volatile("s_waitcnt vmcnt(0)" ::: "memory");
        __builtin_amdgcn_s_barrier();
        __builtin_amdgcn_sched_barrier(0);
        compute(buf);
        __builtin_amdgcn_sched_barrier(0);
        __builtin_amdgcn_s_barrier();
        if (kt + 2 < 8) stage(kt + 2, buf);
    }

    const bool last_tiles = (mt >= 510);
#pragma unroll
    for (int mi = 0; mi < 2; ++mi) {
#pragma unroll
        for (int ni = 0; ni < 4; ++ni) {
            int col = n0 + wn * 64 + ni * 16 + llo;
            int rowb = m0 + wm * 32 + mi * 16 + lhi * 4;
#pragma unroll
            for (int r = 0; r < 4; ++r) {
                int row = rowb + r;
                float v = acc[mi][ni][r] + biasall[(row & 127) * H_DIM + col];
                v = fmaxf(v, 0.0f);
                C[(size_t)row * H_DIM + col] = v;
                if (last_tiles) Clast[(row & 127) * H_DIM + col] = v;
            }
        }
    }
}

// ---------------------------------------------------------------------------
// Fallback reg-staged f32 GEMM (bench-passed lineage) if ws too small.
// ---------------------------------------------------------------------------
__global__ __launch_bounds__(256, 2) void gemm_bt(
    const float* __restrict__ A, const float* __restrict__ Bm,
    int M, int N, int K, const float* __restrict__ bias0,
    float* __restrict__ C, float* __restrict__ Clast) {
    __shared__ unsigned short As[128 * 64];
    __shared__ unsigned short Bs[128 * 64];
    const int tid = threadIdx.x;
    const int wid = tid >> 6, lane = tid & 63;
    const int wr = wid >> 1, wc = wid & 1;
    const int lhi = lane >> 4, llo = lane & 15;
    const int orig = blockIdx.x, nwg = gridDim.x;
    const int wg = (nwg > 8 && (nwg & 7) == 0)
                       ? ((orig & 7) * (nwg >> 3) + (orig >> 3)) : orig;
    const int m0 = (wg >> 3) * 128, n0 = (wg & 7) * 128;
    const int srow = tid >> 3, c8 = tid & 7;
    const int slot8 = (c8 ^ (srow & 7)) * 8;
    const float* Aptr = A + (size_t)(m0 + srow) * K + c8 * 8;
    const float* Bptr = Bm + (size_t)(n0 + srow) * K + c8 * 8;
    f32x4 pf[2][4][2];
    auto issue = [&](int k0) {
#pragma unroll
        for (int g = 0; g < 4; ++g) {
            const float* pa = Aptr + (size_t)g * 32 * K + k0;
            const float* pb = Bptr + (size_t)g * 32 * K + k0;
            pf[0][g][0] = *(const f32x4*)pa; pf[0][g][1] = *(const f32x4*)(pa + 4);
            pf[1][g][0] = *(const f32x4*)pb; pf[1][g][1] = *(const f32x4*)(pb + 4);
        }
    };
    auto write_lds = [&]() {
#pragma unroll
        for (int g = 0; g < 4; ++g) {
            union { unsigned short s[8]; short8 v; } pka, pkb;
#pragma unroll
            for (int j = 0; j < 4; ++j) {
                pka.s[j] = f2bf(pf[0][g][0][j]); pka.s[4 + j] = f2bf(pf[0][g][1][j]);
                pkb.s[j] = f2bf(pf[1][g][0][j]); pkb.s[4 + j] = f2bf(pf[1][g][1][j]);
            }
            *(short8*)&As[(srow + g * 32) * 64 + slot8] = pka.v;
            *(short8*)&Bs[(srow + g * 32) * 64 + slot8] = pkb.v;
        }
    };
    f32x4 acc[4][4] = {};
    auto compute = [&]() {
#pragma unroll
        for (int ks = 0; ks < 2; ++ks) {
            short8 afr[4], bfr[4];
#pragma unroll
            for (int mi = 0; mi < 4; ++mi) {
                int ar = wr * 64 + mi * 16 + llo;
                afr[mi] = *(const short8*)&As[ar * 64 + (((ks << 2) + lhi) ^ (ar & 7)) * 8];
            }
#pragma unroll
            for (int ni = 0; ni < 4; ++ni) {
                int br = wc * 64 + ni * 16 + llo;
                bfr[ni] = *(const short8*)&Bs[br * 64 + (((ks << 2) + lhi) ^ (br & 7)) * 8];
            }
#pragma unroll
            for (int mi = 0; mi < 4; ++mi)
#pragma unroll
                for (int ni = 0; ni < 4; ++ni)
                    acc[mi][ni] = __builtin_amdgcn_mfma_f32_16x16x32_bf16(
                        afr[mi], bfr[ni], acc[mi][ni], 0, 0, 0);
        }
    };
    issue(0); write_lds(); __syncthreads();
    for (int k0 = 64; k0 < K; k0 += 64) {
        issue(k0); compute(); __syncthreads(); write_lds(); __syncthreads();
    }
    compute();
    const bool last_tile = (m0 == M - 128);
#pragma unroll
    for (int mi = 0; mi < 4; ++mi)
#pragma unroll
        for (int ni = 0; ni < 4; ++ni) {
            int col = n0 + wc * 64 + ni * 16 + llo;
            int rowb = m0 + wr * 64 + mi * 16 + lhi * 4;
#pragma unroll
            for (int r = 0; r < 4; ++r) {
                int row = rowb + r;
                float v = fmaxf(acc[mi][ni][r] + bias0[(row & 127) * N + col], 0.f);
                C[(size_t)row * N + col] = v;
                if (last_tile) Clast[(row & 127) * N + col] = v;
            }
        }
}

extern "C" void kernel_launch(void* const* d_in, const int* in_sizes, int n_in,
                              void* d_out, int out_size, void* d_ws, size_t ws_size,
                              hipStream_t stream) {
    const float* x = (const float*)d_in[0];       // (T,B,I)
    const float* hidden = (const float*)d_in[1];  // (B,H)
    const float* W_ih = (const float*)d_in[2];    // (H,I)
    const float* W_hh = (const float*)d_in[3];    // (H,H)
    const float* b_ih = (const float*)d_in[4];    // (H,)
    const float* b_hh = (const float*)d_in[5];    // (H,)

    float* out = (float*)d_out;                              // (T,B,H)
    float* out_last = out + (size_t)T_DIM * B_DIM * H_DIM;   // (B,H)

    // ws: [0,512K) biasall f32 ; then Xp (256 tiles x 128 KB) ; Wp (8 tiles)
    float* biasall = (float*)d_ws;
    unsigned short* Xp = (unsigned short*)((char*)d_ws + 512 * 1024);
    unsigned short* Wp = Xp + (size_t)256 * 65536;
    const size_t ws_need = 512 * 1024 + (size_t)264 * 65536 * 2;

    if (ws_size >= ws_need) {
        prep<true><<<dim3(PACK_BLOCKS + BIAS_BLOCKS), dim3(256), 0, stream>>>(
            x, W_ih, Xp, hidden, W_hh, b_ih, b_hh, biasall);
        gemm64<<<dim3(4096), dim3(256), 0, stream>>>(Xp, Wp, biasall, out, out_last);
    } else {
        prep<false><<<dim3(BIAS_BLOCKS), dim3(256), 0, stream>>>(
            x, W_ih, nullptr, hidden, W_hh, b_ih, b_hh, biasall);
        gemm_bt<<<dim3(M_DIM / 128 * (H_DIM / 128)), dim3(256), 0, stream>>>(
            x, W_ih, M_DIM, H_DIM, I_DIM, biasall, out, out_last);
    }
}